// Round 7
// baseline (153.536 us; speedup 1.0000x reference)
//
#include <hip/hip_runtime.h>
#include <hip/hip_bf16.h>

#define BB 2
#define TT 15
#define NN 2048
#define TO 8
#define MM 64
#define KH 32
#define DIMD 512
#define R2 0.49f

// DPP cross-lane helpers (VALU)
template<int CTRL>
__device__ __forceinline__ float dppf(float x) {
    return __int_as_float(__builtin_amdgcn_update_dpp(
        __float_as_int(x), __float_as_int(x), CTRL, 0xF, 0xF, false));
}
template<int CTRL>
__device__ __forceinline__ unsigned dppu(unsigned x) {
    return (unsigned)__builtin_amdgcn_update_dpp((int)x, (int)x, CTRL, 0xF, 0xF, false);
}

// key = (bits(v) << 32) | (2048 - i): u64 max == (max v, tie -> min index).
__device__ __forceinline__ bool keyGT(unsigned ahi, unsigned alo, unsigned bhi, unsigned blo) {
    unsigned long long a = (((unsigned long long)ahi) << 32) | alo;
    unsigned long long b = (((unsigned long long)bhi) << 32) | blo;
    return a > b;
}

// ---------------- FPS v7: PROBE — run the full FPS loop TWICE (bit-identical passes) ----------------
// dur = F + 2P vs v6's F + P = 71us. Splits fixed/ramp overhead F from per-pass cost P.
// one block per (b,f) frame; orig frame t = 2f
__global__ __launch_bounds__(256) void fps_kernel(const float* __restrict__ input,
                                                  float* __restrict__ anchor_xyz) {
    __shared__ float4 sA[2][4];   // (keyhi, keylo, x, y) per wave
    __shared__ float  sB[2][4];   // z per wave
    __shared__ float  wout[MM * 3];   // staged winner coords
    int blk = blockIdx.x;            // 0..15 = b*8+f
    int b = blk >> 3, f = blk & 7;
    const float* src = input + ((size_t)(b * TT + 2 * f)) * NN * 3;
    int tid = threadIdx.x, w = tid >> 6;

    // thread t owns consecutive points [8t, 8t+8) in registers
    float px[8], py[8], pz[8], mind[8];
    unsigned lo_[8];                 // 2048 - global_index, precomputed
    const float4* s4 = (const float4*)(src + tid * 24);
    float4 v0 = s4[0], v1 = s4[1], v2 = s4[2], v3 = s4[3], v4 = s4[4], v5 = s4[5];
    px[0] = v0.x; py[0] = v0.y; pz[0] = v0.z;
    px[1] = v0.w; py[1] = v1.x; pz[1] = v1.y;
    px[2] = v1.z; py[2] = v1.w; pz[2] = v2.x;
    px[3] = v2.y; py[3] = v2.z; pz[3] = v2.w;
    px[4] = v3.x; py[4] = v3.y; pz[4] = v3.z;
    px[5] = v3.w; py[5] = v4.x; pz[5] = v4.y;
    px[6] = v4.z; py[6] = v4.w; pz[6] = v5.x;
    px[7] = v5.y; py[7] = v5.z; pz[7] = v5.w;
#pragma unroll
    for (int j = 0; j < 8; ++j) lo_[j] = (unsigned)(NN - (tid * 8 + j));

    float lx0 = src[0], ly0 = src[1], lz0 = src[2];   // seed (broadcast)

    for (int pass = 0; pass < 2; ++pass) {
#pragma unroll
        for (int j = 0; j < 8; ++j) mind[j] = 1e10f;
        float lx = lx0, ly = ly0, lz = lz0;
        if (tid == 0) { wout[0] = lx; wout[1] = ly; wout[2] = lz; }

        for (int it = 1; it < MM; ++it) {
            int pp = it & 1;
            // distance update (no-FMA, fixed order to match numpy bitwise)
            float mv[8];
#pragma unroll
            for (int j = 0; j < 8; ++j) {
                float dx = px[j] - lx, dy = py[j] - ly, dz = pz[j] - lz;
                float d = __fadd_rn(__fadd_rn(__fmul_rn(dx, dx), __fmul_rn(dy, dy)),
                                    __fmul_rn(dz, dz));
                float m = fminf(mind[j], d);
                mind[j] = m;
                mv[j] = m;
            }
            // tree argmax over the 8 candidates (assoc+comm -> order-free)
            unsigned chi[8], clo[8];
            float cx[8], cy[8], cz[8];
#pragma unroll
            for (int j = 0; j < 8; ++j) {
                chi[j] = __float_as_uint(mv[j]); clo[j] = lo_[j];
                cx[j] = px[j]; cy[j] = py[j]; cz[j] = pz[j];
            }
#pragma unroll
            for (int st = 1; st < 8; st <<= 1) {
#pragma unroll
                for (int j = 0; j < 8; j += 2 * st) {
                    if (keyGT(chi[j + st], clo[j + st], chi[j], clo[j])) {
                        chi[j] = chi[j + st]; clo[j] = clo[j + st];
                        cx[j] = cx[j + st]; cy[j] = cy[j + st]; cz[j] = cz[j + st];
                    }
                }
            }
            unsigned khi = chi[0], klo = clo[0];
            float wx = cx[0], wy = cy[0], wz = cz[0];

            // wave argmax via DPP (VALU pipe): full result lands in lane 63
#define DPP_STEP(CTRL) { \
            unsigned ohi = dppu<CTRL>(khi), olo = dppu<CTRL>(klo); \
            float ox = dppf<CTRL>(wx), oy = dppf<CTRL>(wy), oz = dppf<CTRL>(wz); \
            if (keyGT(ohi, olo, khi, klo)) { khi = ohi; klo = olo; wx = ox; wy = oy; wz = oz; } }
            DPP_STEP(0xB1)   // quad_perm xor1
            DPP_STEP(0x4E)   // quad_perm xor2
            DPP_STEP(0x141)  // row_half_mirror
            DPP_STEP(0x140)  // row_mirror
            DPP_STEP(0x142)  // row_bcast15
            DPP_STEP(0x143)  // row_bcast31
#undef DPP_STEP
            if ((tid & 63) == 63) {
                sA[pp][w] = make_float4(__uint_as_float(khi), __uint_as_float(klo), wx, wy);
                sB[pp][w] = wz;
            }
            __syncthreads();
            float4 a0 = sA[pp][0], a1 = sA[pp][1], a2 = sA[pp][2], a3 = sA[pp][3];
            float b0 = sB[pp][0], b1 = sB[pp][1], b2 = sB[pp][2], b3 = sB[pp][3];
            unsigned h0 = __float_as_uint(a0.x), l0 = __float_as_uint(a0.y);
            unsigned h1 = __float_as_uint(a1.x), l1 = __float_as_uint(a1.y);
            unsigned h2 = __float_as_uint(a2.x), l2 = __float_as_uint(a2.y);
            unsigned h3 = __float_as_uint(a3.x), l3 = __float_as_uint(a3.y);
            if (keyGT(h1, l1, h0, l0)) { h0 = h1; l0 = l1; a0.z = a1.z; a0.w = a1.w; b0 = b1; }
            if (keyGT(h3, l3, h2, l2)) { h2 = h3; l2 = l3; a2.z = a3.z; a2.w = a3.w; b2 = b3; }
            if (keyGT(h2, l2, h0, l0)) { h0 = h2; l0 = l2; a0.z = a2.z; a0.w = a2.w; b0 = b2; }
            lx = a0.z; ly = a0.w; lz = b0;   // block-uniform winner coords
            if (tid == 0) { wout[it * 3 + 0] = lx; wout[it * 3 + 1] = ly; wout[it * 3 + 2] = lz; }
        }
        __syncthreads();   // isolate passes (WAR on ping-pong slots)
    }

    // one coalesced global write of all winners at the end
    float* out = anchor_xyz + (size_t)blk * MM * 3;
    if (tid < MM * 3) out[tid] = wout[tid];
}

// ---------------- Encode: one block per anchor (b,f,m); 256 threads = 2 dims each ----------------
__global__ __launch_bounds__(256) void encode_kernel(const float* __restrict__ input,
                                                     const float* __restrict__ W_d,
                                                     const float* __restrict__ W_f,
                                                     const float* __restrict__ W_pos,
                                                     const float* __restrict__ b_pos,
                                                     const float* __restrict__ anchor_xyz,
                                                     float* __restrict__ outp) {
    __shared__ float hx[2][KH], hy[2][KH], hz[2][KH];
    __shared__ int swtot[2][4];
    int bid = blockIdx.x;                 // b*512 + f*64 + m
    int b = bid >> 9;
    int rem = bid & 511;
    int f = rem >> 6;
    int m = rem & 63;
    int tid = threadIdx.x, lane = tid & 63, w = tid >> 6;

    const float* anc = anchor_xyz + (size_t)(((b << 3) + f) * MM + m) * 3;
    float ax = anc[0], ay = anc[1], az = anc[2];

    int d0 = tid, d1 = tid + 256;
    float4 wd0 = ((const float4*)W_d)[d0];
    float4 wd1 = ((const float4*)W_d)[d1];
    float  wf0 = W_f[d0], wf1 = W_f[d1];
    float p0 = -INFINITY, p1 = -INFINITY;

    for (int dt = -1; dt <= 1; ++dt) {
        int pp = (dt + 1) & 1;
        int frame = 2 * f + dt;
        frame = frame < 0 ? 0 : (frame > 14 ? 14 : frame);
        const float* src = input + ((size_t)(b * TT + frame)) * NN * 3;

        // thread t owns consecutive points [8t, 8t+8)
        float px[8], py[8], pz[8];
        const float4* s4 = (const float4*)(src + tid * 24);
        float4 v0 = s4[0], v1 = s4[1], v2 = s4[2], v3 = s4[3], v4 = s4[4], v5 = s4[5];
        px[0] = v0.x; py[0] = v0.y; pz[0] = v0.z;
        px[1] = v0.w; py[1] = v1.x; pz[1] = v1.y;
        px[2] = v1.z; py[2] = v1.w; pz[2] = v2.x;
        px[3] = v2.y; py[3] = v2.z; pz[3] = v2.w;
        px[4] = v3.x; py[4] = v3.y; pz[4] = v3.z;
        px[5] = v3.w; py[5] = v4.x; pz[5] = v4.y;
        px[6] = v4.z; py[6] = v4.w; pz[6] = v5.x;
        px[7] = v5.y; py[7] = v5.z; pz[7] = v5.w;

        unsigned hit = 0; int cnt = 0;
#pragma unroll
        for (int j = 0; j < 8; ++j) {
            float dx = ax - px[j], dy = ay - py[j], dz = az - pz[j];
            float d2 = __fadd_rn(__fadd_rn(__fmul_rn(dx, dx), __fmul_rn(dy, dy)),
                                 __fmul_rn(dz, dz));
            if (d2 < R2) { hit |= 1u << j; cnt++; }
        }
        // wave inclusive scan of cnt
        int s = cnt;
#pragma unroll
        for (int off = 1; off < 64; off <<= 1) {
            int o = __shfl_up(s, off);
            if (lane >= off) s += o;
        }
        if (lane == 63) swtot[pp][w] = s;
        __syncthreads();
        int wavebase = 0, total = 0;
#pragma unroll
        for (int ww = 0; ww < 4; ++ww) {
            int t2 = swtot[pp][ww];
            total += t2;
            if (ww < w) wavebase += t2;
        }
        int r = wavebase + s - cnt;   // exclusive global rank of this thread's first hit
#pragma unroll
        for (int j = 0; j < 8; ++j) {
            if (hit & (1u << j)) {
                if (r < KH) { hx[pp][r] = px[j]; hy[pp][r] = py[j]; hz[pp][r] = pz[j]; }
                r++;
            }
        }
        if (total == 0 && tid == 0) { hx[pp][0] = px[0]; hy[pp][0] = py[0]; hz[pp][0] = pz[0]; }
        __syncthreads();

        int nh = (total == 0) ? 1 : (total < KH ? total : KH);
        float dtf = (float)dt;
        // dual accumulators halve the dependent fmax chain (max is exactly assoc+comm)
        float q0 = -INFINITY, q1 = -INFINITY;
        int k = 0;
        for (; k + 2 <= nh; k += 2) {
            float gx0 = hx[pp][k],     gy0 = hy[pp][k],     gz0 = hz[pp][k];
            float gx1 = hx[pp][k + 1], gy1 = hy[pp][k + 1], gz1 = hz[pp][k + 1];
            float dx0 = gx0 - ax, dy0 = gy0 - ay, dz0 = gz0 - az;
            float dx1 = gx1 - ax, dy1 = gy1 - ay, dz1 = gz1 - az;
            float u0 = dx0 * wd0.x + dy0 * wd0.y + dz0 * wd0.z + dtf * wd0.w + gz0 * wf0;
            float u1 = dx0 * wd1.x + dy0 * wd1.y + dz0 * wd1.z + dtf * wd1.w + gz0 * wf1;
            float t0 = dx1 * wd0.x + dy1 * wd0.y + dz1 * wd0.z + dtf * wd0.w + gz1 * wf0;
            float t1 = dx1 * wd1.x + dy1 * wd1.y + dz1 * wd1.z + dtf * wd1.w + gz1 * wf1;
            p0 = fmaxf(p0, u0); p1 = fmaxf(p1, u1);
            q0 = fmaxf(q0, t0); q1 = fmaxf(q1, t1);
        }
        if (k < nh) {
            float gx0 = hx[pp][k], gy0 = hy[pp][k], gz0 = hz[pp][k];
            float dx0 = gx0 - ax, dy0 = gy0 - ay, dz0 = gz0 - az;
            float u0 = dx0 * wd0.x + dy0 * wd0.y + dz0 * wd0.z + dtf * wd0.w + gz0 * wf0;
            float u1 = dx0 * wd1.x + dy0 * wd1.y + dz0 * wd1.z + dtf * wd1.w + gz0 * wf1;
            p0 = fmaxf(p0, u0); p1 = fmaxf(p1, u1);
        }
        p0 = fmaxf(p0, q0); p1 = fmaxf(p1, q1);
        // no trailing barrier: ping-pong buffers handle WAR across dt
    }

    // epilogue: positional linear + bias + relu, float32 store
    float4 wp0 = ((const float4*)W_pos)[d0];
    float4 wp1 = ((const float4*)W_pos)[d1];
    float tv = (float)(f + 1);
    float pos0 = ax * wp0.x + ay * wp0.y + az * wp0.z + tv * wp0.w + b_pos[d0];
    float pos1 = ax * wp1.x + ay * wp1.y + az * wp1.z + tv * wp1.w + b_pos[d1];
    float o0 = fmaxf(pos0 + p0, 0.0f);
    float o1 = fmaxf(pos1 + p1, 0.0f);
    size_t row = ((size_t)b * (TO * MM) + f * MM + m) * DIMD;
    outp[row + d0] = o0;
    outp[row + d1] = o1;
}

extern "C" void kernel_launch(void* const* d_in, const int* in_sizes, int n_in,
                              void* d_out, int out_size, void* d_ws, size_t ws_size,
                              hipStream_t stream) {
    const float* input = (const float*)d_in[0];
    const float* W_d   = (const float*)d_in[1];
    const float* W_f   = (const float*)d_in[2];
    const float* W_pos = (const float*)d_in[3];
    const float* b_pos = (const float*)d_in[4];
    float* anchor = (float*)d_ws;   // 16*64*3 floats = 12 KB

    fps_kernel<<<16, 256, 0, stream>>>(input, anchor);
    encode_kernel<<<1024, 256, 0, stream>>>(input, W_d, W_f, W_pos, b_pos, anchor,
                                            (float*)d_out);
}

// Round 8
// 127.569 us; speedup vs baseline: 1.2036x; 1.2036x over previous
//
#include <hip/hip_runtime.h>
#include <hip/hip_bf16.h>

#define BB 2
#define TT 15
#define NN 2048
#define TO 8
#define MM 64
#define KH 32
#define DIMD 512
#define R2 0.49f

// DPP cross-lane helpers (VALU)
template<int CTRL>
__device__ __forceinline__ unsigned dppu(unsigned x) {
    return (unsigned)__builtin_amdgcn_update_dpp((int)x, (int)x, CTRL, 0xF, 0xF, false);
}

// key = (bits(v) << 32) | (2048 - i): u64 max == (max v, tie -> min index).
__device__ __forceinline__ bool keyGT(unsigned ahi, unsigned alo, unsigned bhi, unsigned blo) {
    unsigned long long a = (((unsigned long long)ahi) << 32) | alo;
    unsigned long long b = (((unsigned long long)bhi) << 32) | blo;
    return a > b;
}

// ---------------- FPS v8: key-only DPP reduce + winner-writes-coords ----------------
// one block per (b,f) frame; orig frame t = 2f
__global__ __launch_bounds__(256) void fps_kernel(const float* __restrict__ input,
                                                  float* __restrict__ anchor_xyz) {
    __shared__ float4 sA[2][4];   // (keyhi, keylo, x, y) per wave
    __shared__ float  sB[2][4];   // z per wave
    __shared__ float  wout[MM * 3];   // staged winner coords
    int blk = blockIdx.x;            // 0..15 = b*8+f
    int b = blk >> 3, f = blk & 7;
    const float* src = input + ((size_t)(b * TT + 2 * f)) * NN * 3;
    int tid = threadIdx.x, w = tid >> 6;

    // thread t owns consecutive points [8t, 8t+8) in registers
    float px[8], py[8], pz[8], mind[8];
    unsigned lo_[8];                 // 2048 - global_index, precomputed
    const float4* s4 = (const float4*)(src + tid * 24);
    float4 v0 = s4[0], v1 = s4[1], v2 = s4[2], v3 = s4[3], v4 = s4[4], v5 = s4[5];
    px[0] = v0.x; py[0] = v0.y; pz[0] = v0.z;
    px[1] = v0.w; py[1] = v1.x; pz[1] = v1.y;
    px[2] = v1.z; py[2] = v1.w; pz[2] = v2.x;
    px[3] = v2.y; py[3] = v2.z; pz[3] = v2.w;
    px[4] = v3.x; py[4] = v3.y; pz[4] = v3.z;
    px[5] = v3.w; py[5] = v4.x; pz[5] = v4.y;
    px[6] = v4.z; py[6] = v4.w; pz[6] = v5.x;
    px[7] = v5.y; py[7] = v5.z; pz[7] = v5.w;
#pragma unroll
    for (int j = 0; j < 8; ++j) {
        mind[j] = 1e10f;
        lo_[j] = (unsigned)(NN - (tid * 8 + j));
    }

    // seed: point 0 (uniform scalar loads, broadcast)
    float lx = src[0], ly = src[1], lz = src[2];
    if (tid == 0) { wout[0] = lx; wout[1] = ly; wout[2] = lz; }

    for (int it = 1; it < MM; ++it) {
        int pp = it & 1;
        // distance update + incremental scan carrying (bv, blo, bx, by, bz)
        float bv = -1.0f, bx = 0.f, by = 0.f, bz = 0.f;
        unsigned blo = 0;
#pragma unroll
        for (int j = 0; j < 8; ++j) {
            float dx = px[j] - lx, dy = py[j] - ly, dz = pz[j] - lz;
            // no-FMA, fixed order: ((dx*dx + dy*dy) + dz*dz) to match numpy bitwise
            float d = __fadd_rn(__fadd_rn(__fmul_rn(dx, dx), __fmul_rn(dy, dy)),
                                __fmul_rn(dz, dz));
            float m = fminf(mind[j], d);
            mind[j] = m;
            // strict > + ascending j == first-occurrence within thread
            if (m > bv) { bv = m; blo = lo_[j]; bx = px[j]; by = py[j]; bz = pz[j]; }
        }
        unsigned khi = __float_as_uint(bv), klo = blo;

        // key-only wave argmax via DPP; full max ends in lanes 48-63
#define DPP_STEP(CTRL) { \
            unsigned ohi = dppu<CTRL>(khi), olo = dppu<CTRL>(klo); \
            if (keyGT(ohi, olo, khi, klo)) { khi = ohi; klo = olo; } }
        DPP_STEP(0xB1)   // quad_perm xor1
        DPP_STEP(0x4E)   // quad_perm xor2
        DPP_STEP(0x141)  // row_half_mirror
        DPP_STEP(0x140)  // row_mirror
        DPP_STEP(0x142)  // row_bcast15
        DPP_STEP(0x143)  // row_bcast31
#undef DPP_STEP
        unsigned maxhi = (unsigned)__builtin_amdgcn_readlane((int)khi, 63);
        unsigned maxlo = (unsigned)__builtin_amdgcn_readlane((int)klo, 63);
        // exactly ONE lane per wave owns this key (index embedded) -> it writes coords
        if (__float_as_uint(bv) == maxhi && blo == maxlo) {
            sA[pp][w] = make_float4(__uint_as_float(maxhi), __uint_as_float(maxlo), bx, by);
            sB[pp][w] = bz;
        }
        __syncthreads();
        float4 a0 = sA[pp][0], a1 = sA[pp][1], a2 = sA[pp][2], a3 = sA[pp][3];
        float b0 = sB[pp][0], b1 = sB[pp][1], b2 = sB[pp][2], b3 = sB[pp][3];
        unsigned h0 = __float_as_uint(a0.x), l0 = __float_as_uint(a0.y);
        unsigned h1 = __float_as_uint(a1.x), l1 = __float_as_uint(a1.y);
        unsigned h2 = __float_as_uint(a2.x), l2 = __float_as_uint(a2.y);
        unsigned h3 = __float_as_uint(a3.x), l3 = __float_as_uint(a3.y);
        if (keyGT(h1, l1, h0, l0)) { h0 = h1; l0 = l1; a0.z = a1.z; a0.w = a1.w; b0 = b1; }
        if (keyGT(h3, l3, h2, l2)) { h2 = h3; l2 = l3; a2.z = a3.z; a2.w = a3.w; b2 = b3; }
        if (keyGT(h2, l2, h0, l0)) { h0 = h2; l0 = l2; a0.z = a2.z; a0.w = a2.w; b0 = b2; }
        lx = a0.z; ly = a0.w; lz = b0;   // block-uniform winner coords
        if (tid == 0) { wout[it * 3 + 0] = lx; wout[it * 3 + 1] = ly; wout[it * 3 + 2] = lz; }
        // single barrier per iter: ping-pong handles WAR; wout drains via lgkmcnt (cheap)
    }

    // one coalesced global write of all winners at the end
    __syncthreads();
    float* out = anchor_xyz + (size_t)blk * MM * 3;
    if (tid < MM * 3) out[tid] = wout[tid];
}

// ---------------- Clock probe: spin 150,000 s_memtime ticks ----------------
// dur_us of this dispatch == 150000 / f_shader. ~62us -> 2.4GHz, ~150us -> 1GHz.
__global__ void clockprobe_kernel(int* sink) {
    unsigned long long start = __builtin_amdgcn_s_memtime();
    unsigned long long now = start;
    int guard = 0;
    while ((now - start) < 150000ULL && guard < 4000000) {
        now = __builtin_amdgcn_s_memtime();
        ++guard;
    }
    if (threadIdx.x == 0) sink[0] = (now >= start) ? 1 : 0;   // constant value, keeps loop live
}

// ---------------- Encode: one block per anchor (b,f,m); 256 threads = 2 dims each ----------------
__global__ __launch_bounds__(256) void encode_kernel(const float* __restrict__ input,
                                                     const float* __restrict__ W_d,
                                                     const float* __restrict__ W_f,
                                                     const float* __restrict__ W_pos,
                                                     const float* __restrict__ b_pos,
                                                     const float* __restrict__ anchor_xyz,
                                                     float* __restrict__ outp) {
    __shared__ float hx[2][KH], hy[2][KH], hz[2][KH];
    __shared__ int swtot[2][4];
    int bid = blockIdx.x;                 // b*512 + f*64 + m
    int b = bid >> 9;
    int rem = bid & 511;
    int f = rem >> 6;
    int m = rem & 63;
    int tid = threadIdx.x, lane = tid & 63, w = tid >> 6;

    const float* anc = anchor_xyz + (size_t)(((b << 3) + f) * MM + m) * 3;
    float ax = anc[0], ay = anc[1], az = anc[2];

    int d0 = tid, d1 = tid + 256;
    float4 wd0 = ((const float4*)W_d)[d0];
    float4 wd1 = ((const float4*)W_d)[d1];
    float  wf0 = W_f[d0], wf1 = W_f[d1];
    float p0 = -INFINITY, p1 = -INFINITY;

    for (int dt = -1; dt <= 1; ++dt) {
        int pp = (dt + 1) & 1;
        int frame = 2 * f + dt;
        frame = frame < 0 ? 0 : (frame > 14 ? 14 : frame);
        const float* src = input + ((size_t)(b * TT + frame)) * NN * 3;

        // thread t owns consecutive points [8t, 8t+8)
        float px[8], py[8], pz[8];
        const float4* s4 = (const float4*)(src + tid * 24);
        float4 v0 = s4[0], v1 = s4[1], v2 = s4[2], v3 = s4[3], v4 = s4[4], v5 = s4[5];
        px[0] = v0.x; py[0] = v0.y; pz[0] = v0.z;
        px[1] = v0.w; py[1] = v1.x; pz[1] = v1.y;
        px[2] = v1.z; py[2] = v1.w; pz[2] = v2.x;
        px[3] = v2.y; py[3] = v2.z; pz[3] = v2.w;
        px[4] = v3.x; py[4] = v3.y; pz[4] = v3.z;
        px[5] = v3.w; py[5] = v4.x; pz[5] = v4.y;
        px[6] = v4.z; py[6] = v4.w; pz[6] = v5.x;
        px[7] = v5.y; py[7] = v5.z; pz[7] = v5.w;

        unsigned hit = 0; int cnt = 0;
#pragma unroll
        for (int j = 0; j < 8; ++j) {
            float dx = ax - px[j], dy = ay - py[j], dz = az - pz[j];
            float d2 = __fadd_rn(__fadd_rn(__fmul_rn(dx, dx), __fmul_rn(dy, dy)),
                                 __fmul_rn(dz, dz));
            if (d2 < R2) { hit |= 1u << j; cnt++; }
        }
        // wave inclusive scan of cnt
        int s = cnt;
#pragma unroll
        for (int off = 1; off < 64; off <<= 1) {
            int o = __shfl_up(s, off);
            if (lane >= off) s += o;
        }
        if (lane == 63) swtot[pp][w] = s;
        __syncthreads();
        int wavebase = 0, total = 0;
#pragma unroll
        for (int ww = 0; ww < 4; ++ww) {
            int t2 = swtot[pp][ww];
            total += t2;
            if (ww < w) wavebase += t2;
        }
        int r = wavebase + s - cnt;   // exclusive global rank of this thread's first hit
#pragma unroll
        for (int j = 0; j < 8; ++j) {
            if (hit & (1u << j)) {
                if (r < KH) { hx[pp][r] = px[j]; hy[pp][r] = py[j]; hz[pp][r] = pz[j]; }
                r++;
            }
        }
        if (total == 0 && tid == 0) { hx[pp][0] = px[0]; hy[pp][0] = py[0]; hz[pp][0] = pz[0]; }
        __syncthreads();

        int nh = (total == 0) ? 1 : (total < KH ? total : KH);
        float dtf = (float)dt;
        // dual accumulators halve the dependent fmax chain (max is exactly assoc+comm)
        float q0 = -INFINITY, q1 = -INFINITY;
        int k = 0;
        for (; k + 2 <= nh; k += 2) {
            float gx0 = hx[pp][k],     gy0 = hy[pp][k],     gz0 = hz[pp][k];
            float gx1 = hx[pp][k + 1], gy1 = hy[pp][k + 1], gz1 = hz[pp][k + 1];
            float dx0 = gx0 - ax, dy0 = gy0 - ay, dz0 = gz0 - az;
            float dx1 = gx1 - ax, dy1 = gy1 - ay, dz1 = gz1 - az;
            float u0 = dx0 * wd0.x + dy0 * wd0.y + dz0 * wd0.z + dtf * wd0.w + gz0 * wf0;
            float u1 = dx0 * wd1.x + dy0 * wd1.y + dz0 * wd1.z + dtf * wd1.w + gz0 * wf1;
            float t0 = dx1 * wd0.x + dy1 * wd0.y + dz1 * wd0.z + dtf * wd0.w + gz1 * wf0;
            float t1 = dx1 * wd1.x + dy1 * wd1.y + dz1 * wd1.z + dtf * wd1.w + gz1 * wf1;
            p0 = fmaxf(p0, u0); p1 = fmaxf(p1, u1);
            q0 = fmaxf(q0, t0); q1 = fmaxf(q1, t1);
        }
        if (k < nh) {
            float gx0 = hx[pp][k], gy0 = hy[pp][k], gz0 = hz[pp][k];
            float dx0 = gx0 - ax, dy0 = gy0 - ay, dz0 = gz0 - az;
            float u0 = dx0 * wd0.x + dy0 * wd0.y + dz0 * wd0.z + dtf * wd0.w + gz0 * wf0;
            float u1 = dx0 * wd1.x + dy0 * wd1.y + dz0 * wd1.z + dtf * wd1.w + gz0 * wf1;
            p0 = fmaxf(p0, u0); p1 = fmaxf(p1, u1);
        }
        p0 = fmaxf(p0, q0); p1 = fmaxf(p1, q1);
        // no trailing barrier: ping-pong buffers handle WAR across dt
    }

    // epilogue: positional linear + bias + relu, float32 store
    float4 wp0 = ((const float4*)W_pos)[d0];
    float4 wp1 = ((const float4*)W_pos)[d1];
    float tv = (float)(f + 1);
    float pos0 = ax * wp0.x + ay * wp0.y + az * wp0.z + tv * wp0.w + b_pos[d0];
    float pos1 = ax * wp1.x + ay * wp1.y + az * wp1.z + tv * wp1.w + b_pos[d1];
    float o0 = fmaxf(pos0 + p0, 0.0f);
    float o1 = fmaxf(pos1 + p1, 0.0f);
    size_t row = ((size_t)b * (TO * MM) + f * MM + m) * DIMD;
    outp[row + d0] = o0;
    outp[row + d1] = o1;
}

extern "C" void kernel_launch(void* const* d_in, const int* in_sizes, int n_in,
                              void* d_out, int out_size, void* d_ws, size_t ws_size,
                              hipStream_t stream) {
    const float* input = (const float*)d_in[0];
    const float* W_d   = (const float*)d_in[1];
    const float* W_f   = (const float*)d_in[2];
    const float* W_pos = (const float*)d_in[3];
    const float* b_pos = (const float*)d_in[4];
    float* anchor = (float*)d_ws;            // 16*64*3 floats = 12 KB
    int* sink = (int*)((char*)d_ws + 16384); // probe sink, outside anchor region

    fps_kernel<<<16, 256, 0, stream>>>(input, anchor);
    clockprobe_kernel<<<1, 64, 0, stream>>>(sink);
    encode_kernel<<<1024, 256, 0, stream>>>(input, W_d, W_f, W_pos, b_pos, anchor,
                                            (float*)d_out);
}

// Round 9
// 111.458 us; speedup vs baseline: 1.3775x; 1.1445x over previous
//
#include <hip/hip_runtime.h>
#include <hip/hip_bf16.h>

#define BB 2
#define TT 15
#define NN 2048
#define TO 8
#define MM 64
#define KH 32
#define DIMD 512
#define R2 0.49f

// DPP cross-lane helper (VALU)
template<int CTRL>
__device__ __forceinline__ unsigned dppu(unsigned x) {
    return (unsigned)__builtin_amdgcn_update_dpp((int)x, (int)x, CTRL, 0xF, 0xF, false);
}

// key = (bits(v) << 32) | (2048 - i): u64 max == (max v, tie -> min index).
__device__ __forceinline__ bool keyGT(unsigned ahi, unsigned alo, unsigned bhi, unsigned blo) {
    unsigned long long a = (((unsigned long long)ahi) << 32) | alo;
    unsigned long long b = (((unsigned long long)bhi) << 32) | blo;
    return a > b;
}

// ---------------- FPS v9: ONE WAVE per frame — no barriers, no LDS combine ----------------
// 16 blocks x 64 threads; thread owns 32 consecutive points in registers.
__global__ __launch_bounds__(64, 1) void fps_kernel(const float* __restrict__ input,
                                                    float* __restrict__ anchor_xyz) {
    __shared__ float wout[MM * 3];   // staged winner coords (written by lane 0 only)
    int blk = blockIdx.x;            // 0..15 = b*8+f
    int b = blk >> 3, f = blk & 7;
    const float* src = input + ((size_t)(b * TT + 2 * f)) * NN * 3;
    int tid = threadIdx.x;           // 0..63, one wave

    // thread t owns consecutive points [32t, 32t+32): 96 floats = 24 float4
    float px[32], py[32], pz[32], mind[32];
    const float4* s4 = (const float4*)(src + tid * 96);
#pragma unroll
    for (int g = 0; g < 8; ++g) {
        float4 a = s4[3 * g], c = s4[3 * g + 1], e = s4[3 * g + 2];
        px[4 * g + 0] = a.x; py[4 * g + 0] = a.y; pz[4 * g + 0] = a.z;
        px[4 * g + 1] = a.w; py[4 * g + 1] = c.x; pz[4 * g + 1] = c.y;
        px[4 * g + 2] = c.z; py[4 * g + 2] = c.w; pz[4 * g + 2] = e.x;
        px[4 * g + 3] = e.y; py[4 * g + 3] = e.z; pz[4 * g + 3] = e.w;
    }
#pragma unroll
    for (int j = 0; j < 32; ++j) mind[j] = 1e10f;

    // seed: point 0 (uniform scalar loads -> SGPR broadcast)
    float lx = src[0], ly = src[1], lz = src[2];
    if (tid == 0) { wout[0] = lx; wout[1] = ly; wout[2] = lz; }

    for (int it = 1; it < MM; ++it) {
        // 4 independent sequential scan chains of 8 points each (ILP), then 3 merges.
        // strict > + ascending j within a chain == numpy first-occurrence;
        // keyGT (min-index tiebreak) across chains/lanes preserves it exactly.
        float bV[4], bX[4], bY[4], bZ[4];
        unsigned bL[4];
#pragma unroll
        for (int c = 0; c < 4; ++c) { bV[c] = -1.0f; bL[c] = 0; bX[c] = 0.f; bY[c] = 0.f; bZ[c] = 0.f; }
#pragma unroll
        for (int k = 0; k < 8; ++k) {
#pragma unroll
            for (int c = 0; c < 4; ++c) {
                int j = c * 8 + k;
                float dx = px[j] - lx, dy = py[j] - ly, dz = pz[j] - lz;
                // no-FMA, fixed order: ((dx*dx + dy*dy) + dz*dz) matches numpy bitwise
                float d = __fadd_rn(__fadd_rn(__fmul_rn(dx, dx), __fmul_rn(dy, dy)),
                                    __fmul_rn(dz, dz));
                float m = fminf(mind[j], d);
                mind[j] = m;
                if (m > bV[c]) {
                    bV[c] = m; bL[c] = (unsigned)(NN - (tid * 32 + j));
                    bX[c] = px[j]; bY[c] = py[j]; bZ[c] = pz[j];
                }
            }
        }
        // merge chains: 1 vs 0, 3 vs 2, then 2-winner vs 0-winner
        if (keyGT(__float_as_uint(bV[1]), bL[1], __float_as_uint(bV[0]), bL[0])) {
            bV[0] = bV[1]; bL[0] = bL[1]; bX[0] = bX[1]; bY[0] = bY[1]; bZ[0] = bZ[1];
        }
        if (keyGT(__float_as_uint(bV[3]), bL[3], __float_as_uint(bV[2]), bL[2])) {
            bV[2] = bV[3]; bL[2] = bL[3]; bX[2] = bX[3]; bY[2] = bY[3]; bZ[2] = bZ[3];
        }
        if (keyGT(__float_as_uint(bV[2]), bL[2], __float_as_uint(bV[0]), bL[0])) {
            bV[0] = bV[2]; bL[0] = bL[2]; bX[0] = bX[2]; bY[0] = bY[2]; bZ[0] = bZ[2];
        }
        unsigned khi = __float_as_uint(bV[0]), klo = bL[0];

        // key-only wave argmax via DPP (validated bit-exact v3-v8); max lands in lane 63
#define DPP_STEP(CTRL) { \
            unsigned ohi = dppu<CTRL>(khi), olo = dppu<CTRL>(klo); \
            if (keyGT(ohi, olo, khi, klo)) { khi = ohi; klo = olo; } }
        DPP_STEP(0xB1)   // quad_perm xor1
        DPP_STEP(0x4E)   // quad_perm xor2
        DPP_STEP(0x141)  // row_half_mirror
        DPP_STEP(0x140)  // row_mirror
        DPP_STEP(0x142)  // row_bcast15
        DPP_STEP(0x143)  // row_bcast31
#undef DPP_STEP
        unsigned maxhi = (unsigned)__builtin_amdgcn_readlane((int)khi, 63);
        unsigned maxlo = (unsigned)__builtin_amdgcn_readlane((int)klo, 63);
        // exactly one lane owns this key (index embedded); broadcast its coords via readlane
        bool winner = (__float_as_uint(bV[0]) == maxhi) && (bL[0] == maxlo);
        unsigned long long mask = __ballot(winner);
        int wlane = (int)(__ffsll((long long)mask) - 1);
        lx = __uint_as_float((unsigned)__builtin_amdgcn_readlane(__float_as_int(bX[0]), wlane));
        ly = __uint_as_float((unsigned)__builtin_amdgcn_readlane(__float_as_int(bY[0]), wlane));
        lz = __uint_as_float((unsigned)__builtin_amdgcn_readlane(__float_as_int(bZ[0]), wlane));
        if (tid == 0) { wout[it * 3 + 0] = lx; wout[it * 3 + 1] = ly; wout[it * 3 + 2] = lz; }
        // single wave: LDS ops are in program order, no barrier needed
    }

    // one coalesced global write of all winners at the end
    float* out = anchor_xyz + (size_t)blk * MM * 3;
#pragma unroll
    for (int i = 0; i < 3; ++i) out[tid + 64 * i] = wout[tid + 64 * i];
}

// ---------------- Encode: one block per anchor (b,f,m); 256 threads = 2 dims each ----------------
__global__ __launch_bounds__(256) void encode_kernel(const float* __restrict__ input,
                                                     const float* __restrict__ W_d,
                                                     const float* __restrict__ W_f,
                                                     const float* __restrict__ W_pos,
                                                     const float* __restrict__ b_pos,
                                                     const float* __restrict__ anchor_xyz,
                                                     float* __restrict__ outp) {
    __shared__ float hx[2][KH], hy[2][KH], hz[2][KH];
    __shared__ int swtot[2][4];
    int bid = blockIdx.x;                 // b*512 + f*64 + m
    int b = bid >> 9;
    int rem = bid & 511;
    int f = rem >> 6;
    int m = rem & 63;
    int tid = threadIdx.x, lane = tid & 63, w = tid >> 6;

    const float* anc = anchor_xyz + (size_t)(((b << 3) + f) * MM + m) * 3;
    float ax = anc[0], ay = anc[1], az = anc[2];

    int d0 = tid, d1 = tid + 256;
    float4 wd0 = ((const float4*)W_d)[d0];
    float4 wd1 = ((const float4*)W_d)[d1];
    float  wf0 = W_f[d0], wf1 = W_f[d1];
    float p0 = -INFINITY, p1 = -INFINITY;

    for (int dt = -1; dt <= 1; ++dt) {
        int pp = (dt + 1) & 1;
        int frame = 2 * f + dt;
        frame = frame < 0 ? 0 : (frame > 14 ? 14 : frame);
        const float* src = input + ((size_t)(b * TT + frame)) * NN * 3;

        // thread t owns consecutive points [8t, 8t+8)
        float px[8], py[8], pz[8];
        const float4* s4 = (const float4*)(src + tid * 24);
        float4 v0 = s4[0], v1 = s4[1], v2 = s4[2], v3 = s4[3], v4 = s4[4], v5 = s4[5];
        px[0] = v0.x; py[0] = v0.y; pz[0] = v0.z;
        px[1] = v0.w; py[1] = v1.x; pz[1] = v1.y;
        px[2] = v1.z; py[2] = v1.w; pz[2] = v2.x;
        px[3] = v2.y; py[3] = v2.z; pz[3] = v2.w;
        px[4] = v3.x; py[4] = v3.y; pz[4] = v3.z;
        px[5] = v3.w; py[5] = v4.x; pz[5] = v4.y;
        px[6] = v4.z; py[6] = v4.w; pz[6] = v5.x;
        px[7] = v5.y; py[7] = v5.z; pz[7] = v5.w;

        unsigned hit = 0; int cnt = 0;
#pragma unroll
        for (int j = 0; j < 8; ++j) {
            float dx = ax - px[j], dy = ay - py[j], dz = az - pz[j];
            float d2 = __fadd_rn(__fadd_rn(__fmul_rn(dx, dx), __fmul_rn(dy, dy)),
                                 __fmul_rn(dz, dz));
            if (d2 < R2) { hit |= 1u << j; cnt++; }
        }
        // wave inclusive scan of cnt
        int s = cnt;
#pragma unroll
        for (int off = 1; off < 64; off <<= 1) {
            int o = __shfl_up(s, off);
            if (lane >= off) s += o;
        }
        if (lane == 63) swtot[pp][w] = s;
        __syncthreads();
        int wavebase = 0, total = 0;
#pragma unroll
        for (int ww = 0; ww < 4; ++ww) {
            int t2 = swtot[pp][ww];
            total += t2;
            if (ww < w) wavebase += t2;
        }
        int r = wavebase + s - cnt;   // exclusive global rank of this thread's first hit
#pragma unroll
        for (int j = 0; j < 8; ++j) {
            if (hit & (1u << j)) {
                if (r < KH) { hx[pp][r] = px[j]; hy[pp][r] = py[j]; hz[pp][r] = pz[j]; }
                r++;
            }
        }
        if (total == 0 && tid == 0) { hx[pp][0] = px[0]; hy[pp][0] = py[0]; hz[pp][0] = pz[0]; }
        __syncthreads();

        int nh = (total == 0) ? 1 : (total < KH ? total : KH);
        float dtf = (float)dt;
        // dual accumulators halve the dependent fmax chain (max is exactly assoc+comm)
        float q0 = -INFINITY, q1 = -INFINITY;
        int k = 0;
        for (; k + 2 <= nh; k += 2) {
            float gx0 = hx[pp][k],     gy0 = hy[pp][k],     gz0 = hz[pp][k];
            float gx1 = hx[pp][k + 1], gy1 = hy[pp][k + 1], gz1 = hz[pp][k + 1];
            float dx0 = gx0 - ax, dy0 = gy0 - ay, dz0 = gz0 - az;
            float dx1 = gx1 - ax, dy1 = gy1 - ay, dz1 = gz1 - az;
            float u0 = dx0 * wd0.x + dy0 * wd0.y + dz0 * wd0.z + dtf * wd0.w + gz0 * wf0;
            float u1 = dx0 * wd1.x + dy0 * wd1.y + dz0 * wd1.z + dtf * wd1.w + gz0 * wf1;
            float t0 = dx1 * wd0.x + dy1 * wd0.y + dz1 * wd0.z + dtf * wd0.w + gz1 * wf0;
            float t1 = dx1 * wd1.x + dy1 * wd1.y + dz1 * wd1.z + dtf * wd1.w + gz1 * wf1;
            p0 = fmaxf(p0, u0); p1 = fmaxf(p1, u1);
            q0 = fmaxf(q0, t0); q1 = fmaxf(q1, t1);
        }
        if (k < nh) {
            float gx0 = hx[pp][k], gy0 = hy[pp][k], gz0 = hz[pp][k];
            float dx0 = gx0 - ax, dy0 = gy0 - ay, dz0 = gz0 - az;
            float u0 = dx0 * wd0.x + dy0 * wd0.y + dz0 * wd0.z + dtf * wd0.w + gz0 * wf0;
            float u1 = dx0 * wd1.x + dy0 * wd1.y + dz0 * wd1.z + dtf * wd1.w + gz0 * wf1;
            p0 = fmaxf(p0, u0); p1 = fmaxf(p1, u1);
        }
        p0 = fmaxf(p0, q0); p1 = fmaxf(p1, q1);
        // no trailing barrier: ping-pong buffers handle WAR across dt
    }

    // epilogue: positional linear + bias + relu, float32 store
    float4 wp0 = ((const float4*)W_pos)[d0];
    float4 wp1 = ((const float4*)W_pos)[d1];
    float tv = (float)(f + 1);
    float pos0 = ax * wp0.x + ay * wp0.y + az * wp0.z + tv * wp0.w + b_pos[d0];
    float pos1 = ax * wp1.x + ay * wp1.y + az * wp1.z + tv * wp1.w + b_pos[d1];
    float o0 = fmaxf(pos0 + p0, 0.0f);
    float o1 = fmaxf(pos1 + p1, 0.0f);
    size_t row = ((size_t)b * (TO * MM) + f * MM + m) * DIMD;
    outp[row + d0] = o0;
    outp[row + d1] = o1;
}

extern "C" void kernel_launch(void* const* d_in, const int* in_sizes, int n_in,
                              void* d_out, int out_size, void* d_ws, size_t ws_size,
                              hipStream_t stream) {
    const float* input = (const float*)d_in[0];
    const float* W_d   = (const float*)d_in[1];
    const float* W_f   = (const float*)d_in[2];
    const float* W_pos = (const float*)d_in[3];
    const float* b_pos = (const float*)d_in[4];
    float* anchor = (float*)d_ws;   // 16*64*3 floats = 12 KB

    fps_kernel<<<16, 64, 0, stream>>>(input, anchor);
    encode_kernel<<<1024, 256, 0, stream>>>(input, W_d, W_f, W_pos, b_pos, anchor,
                                            (float*)d_out);
}

// Round 10
// 50.018 us; speedup vs baseline: 3.0696x; 2.2284x over previous
//
#include <hip/hip_runtime.h>
#include <hip/hip_bf16.h>

#define BB 2
#define TT 15
#define NN 2048
#define TO 8
#define MM 64
#define KH 32
#define DIMD 512
#define R2 0.49f

typedef float v2f __attribute__((ext_vector_type(2)));
typedef unsigned long long ull;

// DPP cross-lane helper (VALU)
template<int CTRL>
__device__ __forceinline__ unsigned dppu(unsigned x) {
    return (unsigned)__builtin_amdgcn_update_dpp((int)x, (int)x, CTRL, 0xF, 0xF, false);
}

// ---------------- FPS v10: pk-math dist + key-only reduce + LDS coord table ----------------
// 16 blocks x 256 threads (4 waves); thread owns 8 consecutive points as 4 float2 pairs.
__global__ __launch_bounds__(256) void fps_kernel(const float* __restrict__ input,
                                                  float* __restrict__ anchor_xyz) {
#pragma clang fp contract(off)
    __shared__ float sxyz[NN * 3];      // 24KB AoS coord table (winner lookup)
    __shared__ ull   sK[2][4];          // per-wave keys, ping-pong
    __shared__ float wout[MM * 3];      // staged winner coords
    int blk = blockIdx.x;               // 0..15 = b*8+f
    int b = blk >> 3, f = blk & 7;
    const float* src = input + ((size_t)(b * TT + 2 * f)) * NN * 3;
    int tid = threadIdx.x, w = tid >> 6;

    // load 8 points (24 floats = 6 float4), stage to LDS, keep in regs as pairs
    const float4* s4 = (const float4*)(src + tid * 24);
    float4 v0 = s4[0], v1 = s4[1], v2 = s4[2], v3 = s4[3], v4 = s4[4], v5 = s4[5];
    float4* l4 = (float4*)(sxyz + tid * 24);
    l4[0] = v0; l4[1] = v1; l4[2] = v2; l4[3] = v3; l4[4] = v4; l4[5] = v5;

    // pair p covers points j=2p, 2p+1 (j local; global index = tid*8+j)
    v2f PX[4], PY[4], PZ[4], MD[4];
    PX[0] = (v2f){v0.x, v0.w}; PY[0] = (v2f){v0.y, v1.x}; PZ[0] = (v2f){v0.z, v1.y};
    PX[1] = (v2f){v1.z, v2.y}; PY[1] = (v2f){v1.w, v2.z}; PZ[1] = (v2f){v2.x, v2.w};
    PX[2] = (v2f){v3.x, v3.w}; PY[2] = (v2f){v3.y, v4.x}; PZ[2] = (v2f){v3.z, v4.y};
    PX[3] = (v2f){v4.z, v5.y}; PY[3] = (v2f){v4.w, v5.z}; PZ[3] = (v2f){v5.x, v5.w};
#pragma unroll
    for (int p = 0; p < 4; ++p) MD[p] = (v2f){1e10f, 1e10f};
    unsigned base = (unsigned)(NN - tid * 8);   // lo_j = base - j

    // seed: point 0 (uniform scalar loads -> broadcast)
    float lx = src[0], ly = src[1], lz = src[2];
    if (tid == 0) { wout[0] = lx; wout[1] = ly; wout[2] = lz; }

    for (int it = 1; it < MM; ++it) {
        int pp = it & 1;
        // packed distance update: v_pk_{add,mul,min}_f32 — IEEE-identical per half,
        // contract(off) keeps ((dx*dx + dy*dy) + dz*dz) mul/add order bitwise.
        v2f L0 = (v2f){lx, lx}, L1 = (v2f){ly, ly}, L2 = (v2f){lz, lz};
#pragma unroll
        for (int p = 0; p < 4; ++p) {
            v2f dx = PX[p] - L0, dy = PY[p] - L1, dz = PZ[p] - L2;
            v2f u1 = dx * dx, u2 = dy * dy, u3 = dz * dz;
            v2f d = (u1 + u2) + u3;
            MD[p] = __builtin_elementwise_min(MD[p], d);
        }
        // keys: (bits(m) << 32) | (2048 - i)  — unique, u64 max == (max m, tie -> min i)
        ull k[8];
#pragma unroll
        for (int p = 0; p < 4; ++p) {
            k[2 * p]     = (((ull)__float_as_uint(MD[p].x)) << 32) | (ull)(base - 2 * p);
            k[2 * p + 1] = (((ull)__float_as_uint(MD[p].y)) << 32) | (ull)(base - 2 * p - 1);
        }
        // in-thread tree (assoc+comm, keys unique -> order-free)
#pragma unroll
        for (int st = 1; st < 8; st <<= 1)
#pragma unroll
            for (int j = 0; j < 8; j += 2 * st)
                if (k[j + st] > k[j]) k[j] = k[j + st];
        unsigned khi = (unsigned)(k[0] >> 32), klo = (unsigned)k[0];

        // key-only wave argmax via DPP; full max lands in lane 63
#define DPP_STEP(CTRL) { \
            unsigned ohi = dppu<CTRL>(khi), olo = dppu<CTRL>(klo); \
            ull ok = (((ull)ohi) << 32) | olo, ck = (((ull)khi) << 32) | klo; \
            if (ok > ck) { khi = ohi; klo = olo; } }
        DPP_STEP(0xB1)   // quad_perm xor1
        DPP_STEP(0x4E)   // quad_perm xor2
        DPP_STEP(0x141)  // row_half_mirror
        DPP_STEP(0x140)  // row_mirror
        DPP_STEP(0x142)  // row_bcast15
        DPP_STEP(0x143)  // row_bcast31
#undef DPP_STEP
        if ((tid & 63) == 63) sK[pp][w] = (((ull)khi) << 32) | klo;
        __syncthreads();
        ull k0 = sK[pp][0], k1 = sK[pp][1], k2 = sK[pp][2], k3 = sK[pp][3];
        if (k1 > k0) k0 = k1;
        if (k3 > k2) k2 = k3;
        if (k2 > k0) k0 = k2;
        unsigned widx = NN - (unsigned)k0;      // block-uniform winner index
        lx = sxyz[3 * widx]; ly = sxyz[3 * widx + 1]; lz = sxyz[3 * widx + 2];  // broadcast reads
        if (tid == 0) { wout[it * 3 + 0] = lx; wout[it * 3 + 1] = ly; wout[it * 3 + 2] = lz; }
        // single barrier per iter: sK ping-pong handles WAR across iterations
    }

    // one coalesced global write of all winners at the end
    __syncthreads();
    float* out = anchor_xyz + (size_t)blk * MM * 3;
    if (tid < MM * 3) out[tid] = wout[tid];
}

// ---------------- Encode: one block per anchor (b,f,m); 256 threads = 2 dims each ----------------
__global__ __launch_bounds__(256) void encode_kernel(const float* __restrict__ input,
                                                     const float* __restrict__ W_d,
                                                     const float* __restrict__ W_f,
                                                     const float* __restrict__ W_pos,
                                                     const float* __restrict__ b_pos,
                                                     const float* __restrict__ anchor_xyz,
                                                     float* __restrict__ outp) {
    __shared__ float hx[2][KH], hy[2][KH], hz[2][KH];
    __shared__ int swtot[2][4];
    int bid = blockIdx.x;                 // b*512 + f*64 + m
    int b = bid >> 9;
    int rem = bid & 511;
    int f = rem >> 6;
    int m = rem & 63;
    int tid = threadIdx.x, lane = tid & 63, w = tid >> 6;

    const float* anc = anchor_xyz + (size_t)(((b << 3) + f) * MM + m) * 3;
    float ax = anc[0], ay = anc[1], az = anc[2];

    int d0 = tid, d1 = tid + 256;
    float4 wd0 = ((const float4*)W_d)[d0];
    float4 wd1 = ((const float4*)W_d)[d1];
    float  wf0 = W_f[d0], wf1 = W_f[d1];
    float p0 = -INFINITY, p1 = -INFINITY;

    for (int dt = -1; dt <= 1; ++dt) {
        int pp = (dt + 1) & 1;
        int frame = 2 * f + dt;
        frame = frame < 0 ? 0 : (frame > 14 ? 14 : frame);
        const float* src = input + ((size_t)(b * TT + frame)) * NN * 3;

        // thread t owns consecutive points [8t, 8t+8)
        float px[8], py[8], pz[8];
        const float4* s4 = (const float4*)(src + tid * 24);
        float4 v0 = s4[0], v1 = s4[1], v2 = s4[2], v3 = s4[3], v4 = s4[4], v5 = s4[5];
        px[0] = v0.x; py[0] = v0.y; pz[0] = v0.z;
        px[1] = v0.w; py[1] = v1.x; pz[1] = v1.y;
        px[2] = v1.z; py[2] = v1.w; pz[2] = v2.x;
        px[3] = v2.y; py[3] = v2.z; pz[3] = v2.w;
        px[4] = v3.x; py[4] = v3.y; pz[4] = v3.z;
        px[5] = v3.w; py[5] = v4.x; pz[5] = v4.y;
        px[6] = v4.z; py[6] = v4.w; pz[6] = v5.x;
        px[7] = v5.y; py[7] = v5.z; pz[7] = v5.w;

        unsigned hit = 0; int cnt = 0;
#pragma unroll
        for (int j = 0; j < 8; ++j) {
            float dx = ax - px[j], dy = ay - py[j], dz = az - pz[j];
            float d2 = __fadd_rn(__fadd_rn(__fmul_rn(dx, dx), __fmul_rn(dy, dy)),
                                 __fmul_rn(dz, dz));
            if (d2 < R2) { hit |= 1u << j; cnt++; }
        }
        // wave inclusive scan of cnt
        int s = cnt;
#pragma unroll
        for (int off = 1; off < 64; off <<= 1) {
            int o = __shfl_up(s, off);
            if (lane >= off) s += o;
        }
        if (lane == 63) swtot[pp][w] = s;
        __syncthreads();
        int wavebase = 0, total = 0;
#pragma unroll
        for (int ww = 0; ww < 4; ++ww) {
            int t2 = swtot[pp][ww];
            total += t2;
            if (ww < w) wavebase += t2;
        }
        int r = wavebase + s - cnt;   // exclusive global rank of this thread's first hit
#pragma unroll
        for (int j = 0; j < 8; ++j) {
            if (hit & (1u << j)) {
                if (r < KH) { hx[pp][r] = px[j]; hy[pp][r] = py[j]; hz[pp][r] = pz[j]; }
                r++;
            }
        }
        if (total == 0 && tid == 0) { hx[pp][0] = px[0]; hy[pp][0] = py[0]; hz[pp][0] = pz[0]; }
        __syncthreads();

        int nh = (total == 0) ? 1 : (total < KH ? total : KH);
        float dtf = (float)dt;
        // dual accumulators halve the dependent fmax chain (max is exactly assoc+comm)
        float q0 = -INFINITY, q1 = -INFINITY;
        int k = 0;
        for (; k + 2 <= nh; k += 2) {
            float gx0 = hx[pp][k],     gy0 = hy[pp][k],     gz0 = hz[pp][k];
            float gx1 = hx[pp][k + 1], gy1 = hy[pp][k + 1], gz1 = hz[pp][k + 1];
            float dx0 = gx0 - ax, dy0 = gy0 - ay, dz0 = gz0 - az;
            float dx1 = gx1 - ax, dy1 = gy1 - ay, dz1 = gz1 - az;
            float u0 = dx0 * wd0.x + dy0 * wd0.y + dz0 * wd0.z + dtf * wd0.w + gz0 * wf0;
            float u1 = dx0 * wd1.x + dy0 * wd1.y + dz0 * wd1.z + dtf * wd1.w + gz0 * wf1;
            float t0 = dx1 * wd0.x + dy1 * wd0.y + dz1 * wd0.z + dtf * wd0.w + gz1 * wf0;
            float t1 = dx1 * wd1.x + dy1 * wd1.y + dz1 * wd1.z + dtf * wd1.w + gz1 * wf1;
            p0 = fmaxf(p0, u0); p1 = fmaxf(p1, u1);
            q0 = fmaxf(q0, t0); q1 = fmaxf(q1, t1);
        }
        if (k < nh) {
            float gx0 = hx[pp][k], gy0 = hy[pp][k], gz0 = hz[pp][k];
            float dx0 = gx0 - ax, dy0 = gy0 - ay, dz0 = gz0 - az;
            float u0 = dx0 * wd0.x + dy0 * wd0.y + dz0 * wd0.z + dtf * wd0.w + gz0 * wf0;
            float u1 = dx0 * wd1.x + dy0 * wd1.y + dz0 * wd1.z + dtf * wd1.w + gz0 * wf1;
            p0 = fmaxf(p0, u0); p1 = fmaxf(p1, u1);
        }
        p0 = fmaxf(p0, q0); p1 = fmaxf(p1, q1);
        // no trailing barrier: ping-pong buffers handle WAR across dt
    }

    // epilogue: positional linear + bias + relu, float32 store
    float4 wp0 = ((const float4*)W_pos)[d0];
    float4 wp1 = ((const float4*)W_pos)[d1];
    float tv = (float)(f + 1);
    float pos0 = ax * wp0.x + ay * wp0.y + az * wp0.z + tv * wp0.w + b_pos[d0];
    float pos1 = ax * wp1.x + ay * wp1.y + az * wp1.z + tv * wp1.w + b_pos[d1];
    float o0 = fmaxf(pos0 + p0, 0.0f);
    float o1 = fmaxf(pos1 + p1, 0.0f);
    size_t row = ((size_t)b * (TO * MM) + f * MM + m) * DIMD;
    outp[row + d0] = o0;
    outp[row + d1] = o1;
}

extern "C" void kernel_launch(void* const* d_in, const int* in_sizes, int n_in,
                              void* d_out, int out_size, void* d_ws, size_t ws_size,
                              hipStream_t stream) {
    const float* input = (const float*)d_in[0];
    const float* W_d   = (const float*)d_in[1];
    const float* W_f   = (const float*)d_in[2];
    const float* W_pos = (const float*)d_in[3];
    const float* b_pos = (const float*)d_in[4];
    float* anchor = (float*)d_ws;   // 16*64*3 floats = 12 KB

    fps_kernel<<<16, 256, 0, stream>>>(input, anchor);
    encode_kernel<<<1024, 256, 0, stream>>>(input, W_d, W_f, W_pos, b_pos, anchor,
                                            (float*)d_out);
}